// Round 4
// baseline (12741.975 us; speedup 1.0000x reference)
//
#include <hip/hip_runtime.h>
#include <stdint.h>

#define BB 64
#define TT 512
#define EE 512
#define HH 1024
#define GG 4096

#define NA0 64
#define NL0 128
#define NA1 128
#define NL1 128
#define NWG (NA0 + NL0 + NA1 + NL1)

#define XP0_SLOTS 8

typedef short v8b __attribute__((ext_vector_type(8)));
typedef float v4f __attribute__((ext_vector_type(4)));
typedef unsigned short u16;
typedef unsigned int u32;
typedef unsigned long long u64;

__device__ __forceinline__ u16 f2bf(float f) {
  union { float f; u32 i; } v; v.f = f;
  u32 u = v.i;
  u32 r = (u + 0x7FFFu + ((u >> 16) & 1u)) >> 16;
  return (u16)r;
}
__device__ __forceinline__ float sigm(float x) { return 1.0f / (1.0f + __expf(-x)); }

// ---- write-through (agent-coherent) stores: data lands in MALL, never dirty in L2 ----
__device__ __forceinline__ void stg16_f(float* p, v4f v) {
  union { v4f f; u64 q[2]; } u; u.f = v;
  __hip_atomic_store((u64*)p,     u.q[0], __ATOMIC_RELAXED, __HIP_MEMORY_SCOPE_AGENT);
  __hip_atomic_store((u64*)p + 1, u.q[1], __ATOMIC_RELAXED, __HIP_MEMORY_SCOPE_AGENT);
}
__device__ __forceinline__ void stg2_h(u16* p, u16 v) {
  __hip_atomic_store(p, v, __ATOMIC_RELAXED, __HIP_MEMORY_SCOPE_AGENT);
}
__device__ __forceinline__ void stg4_f(float* p, float v) {
  union { float f; u32 i; } uv; uv.f = v;
  __hip_atomic_store((u32*)p, uv.i, __ATOMIC_RELAXED, __HIP_MEMORY_SCOPE_AGENT);
}
// drain this wave's outstanding stores to the coherence point (MALL)
__device__ __forceinline__ void drain_stores() {
  asm volatile("s_waitcnt vmcnt(0)" ::: "memory");
}
// acquire: flash-invalidate stale L1/L2 lines so cached loads refetch from MALL
__device__ __forceinline__ void acq_fence() {
  __builtin_amdgcn_fence(__ATOMIC_ACQUIRE, "agent");
}

// ---------------- prep: gather embeddings (fp32 -> bf16), zero counters + h rings, lens -------
__global__ void prep_kernel(const int* __restrict__ x, const float* __restrict__ emb,
                            u16* __restrict__ e16, u16* __restrict__ h0r, u16* __restrict__ h1r,
                            int* __restrict__ lens, u32* cnts, int cnt_u32s) {
  long stride = (long)gridDim.x * blockDim.x;
  long gid = (long)blockIdx.x * blockDim.x + threadIdx.x;
  const long totalE = (long)BB * TT * EE;
  for (long i = gid; i < totalE; i += stride) {
    int d = (int)(i % EE);
    long bt = i / EE;  // b*T + t
    int tok = x[bt];
    e16[i] = f2bf(emb[(long)tok * EE + d]);
  }
  for (long i = gid; i < (long)cnt_u32s; i += stride) cnts[i] = 0u;
  const long ringN = 4L * BB * HH;
  for (long i = gid; i < ringN; i += stride) { h0r[i] = 0; h1r[i] = 0; }
  int gwave = (int)(gid >> 6);
  int lane = (int)(gid & 63);
  if (gwave < BB) {
    int cnt = 0;
    for (int t2 = lane; t2 < TT; t2 += 64) cnt += (x[gwave * TT + t2] == 0) ? 1 : 0;
    for (int off = 32; off; off >>= 1) cnt += __shfl_down(cnt, off, 64);
    if (lane == 0) lens[gwave] = TT - cnt;
  }
}

// ---------------- sync helpers: per-round counters in MALL ----------------
__device__ __forceinline__ void spin_ge(u32* c, u32 n) {
  while (__hip_atomic_load(c, __ATOMIC_RELAXED, __HIP_MEMORY_SCOPE_AGENT) < n)
    __builtin_amdgcn_s_sleep(2);
}
__device__ __forceinline__ void bump(u32* c) {
  if (threadIdx.x == 0)
    __hip_atomic_fetch_add(c, 1u, __ATOMIC_RELAXED, __HIP_MEMORY_SCOPE_AGENT);
}

// ---------------- persistent pipeline kernel ----------------
__global__ __launch_bounds__(256, 2) void lstm_persist(
    const u16* __restrict__ e16,
    const float* __restrict__ Wih0, const float* __restrict__ Whh0, const float* __restrict__ b0,
    const float* __restrict__ Wih1, const float* __restrict__ Whh1, const float* __restrict__ b1,
    const int* __restrict__ lens,
    float* __restrict__ xp0, float* __restrict__ xp1,
    u16* __restrict__ h0r, u16* __restrict__ h1r,
    float* __restrict__ lasth,
    u32* cA0, u32* cL0, u32* cA1, u32* cL1) {
  __shared__ __align__(16) short Wlds[32768];  // 64 KB weight slice, [K/8][rows][8] bf16
  const int wg = blockIdx.x;
  const int tid = threadIdx.x;
  const int wave = tid >> 6;
  const int lane = tid & 63;
  const int m16 = lane & 15;
  const int q = lane >> 4;
  const int bm = wave * 16 + m16;    // A-frag batch row (M dim)
  const int bq = wave * 16 + q * 4;  // C-tile batch base for this lane (M = quad*4+reg)

  if (wg < NA0) {
    // ================= A0: xp0[t] = W_ih0 @ e_t + b0  (rows rbase..rbase+63, K=512) ==========
    const int rbase = wg * 64;
    for (int c2 = tid; c2 < 64 * 64; c2 += 256) {
      int r = c2 >> 6, kb = c2 & 63;
      const float* src = Wih0 + (long)(rbase + r) * EE + kb * 8;
      v8b w;
#pragma unroll
      for (int j = 0; j < 8; ++j) w[j] = (short)f2bf(src[j]);
      *(v8b*)&Wlds[(kb * 64 + r) * 8] = w;
    }
    __syncthreads();
    float bias[4];
#pragma unroll
    for (int nt = 0; nt < 4; ++nt) bias[nt] = b0[rbase + nt * 16 + m16];
    for (int t = 0; t < TT; ++t) {
      if (tid == 0 && t >= XP0_SLOTS) spin_ge(&cL0[t - XP0_SLOTS], NL0);  // ring back-pressure
      __syncthreads();
      // reads only e16 (static) — no acquire fence needed
      v4f acc[4] = {{0.f,0.f,0.f,0.f},{0.f,0.f,0.f,0.f},{0.f,0.f,0.f,0.f},{0.f,0.f,0.f,0.f}};
      const u16* ap = e16 + (long)bm * (TT * EE) + (long)t * EE + q * 8;
#pragma unroll 4
      for (int k0 = 0; k0 < EE; k0 += 32) {
        v8b a = *(const v8b*)(ap + k0);
#pragma unroll
        for (int nt = 0; nt < 4; ++nt) {
          v8b w = *(const v8b*)&Wlds[(((k0 >> 3) + q) * 64 + nt * 16 + m16) * 8];
          acc[nt] = __builtin_amdgcn_mfma_f32_16x16x32_bf16(a, w, acc[nt], 0, 0, 0);
        }
      }
      const int slot = t & (XP0_SLOTS - 1);
#pragma unroll
      for (int nt = 0; nt < 4; ++nt) {
        int n = rbase + nt * 16 + m16;
        v4f v = acc[nt] + bias[nt];
        stg16_f(&xp0[(long)slot * (GG * BB) + (long)n * BB + bq], v);
      }
      drain_stores();
      __syncthreads();
      bump(&cA0[t]);
    }
  } else if (wg < NA0 + NL0) {
    // ================= L0: gates = xp0 + W_hh0 @ h0[t-1]; cell update (8 units) ==============
    const int uwg = wg - NA0;
    const int ubase = uwg * 8;
    for (int c2 = tid; c2 < 32 * 128; c2 += 256) {
      int r = c2 >> 7, kb = c2 & 127;
      int grow = (r >> 3) * HH + ubase + (r & 7);  // rows ordered [i0..7|f0..7|g0..7|o0..7]
      const float* src = Whh0 + (long)grow * HH + kb * 8;
      v8b w;
#pragma unroll
      for (int j = 0; j < 8; ++j) w[j] = (short)f2bf(src[j]);
      *(v8b*)&Wlds[(kb * 32 + r) * 8] = w;
    }
    __syncthreads();
    const int gi0 = (m16 >> 3);
    const int j0 = m16 & 7;
    const int row0 = gi0 * HH + ubase + j0;        // i (m16<8) or f
    const int row1 = (2 + gi0) * HH + ubase + j0;  // g (m16<8) or o
    const bool lo = (m16 < 8);
    float cst[4] = {0.f, 0.f, 0.f, 0.f};
    for (int t = 0; t < TT; ++t) {
      if (tid == 0) spin_ge(&cA0[t], NA0);
      if (tid == 1 && t >= 1) spin_ge(&cL0[t - 1], NL0);
      if (tid == 2 && t >= 4) spin_ge(&cA1[t - 4], NA1);  // h0 ring back-pressure
      __syncthreads();
      acq_fence();  // per-wave: drop stale h0/xp0 lines; refill comes fresh from MALL
      const float* xpS = xp0 + (long)(t & (XP0_SLOTS - 1)) * (GG * BB);
      v4f x0 = *(const v4f*)&xpS[(long)row0 * BB + bq];
      v4f x1 = *(const v4f*)&xpS[(long)row1 * BB + bq];
      const u16* hp = h0r + ((t + 3) & 3) * (BB * HH) + bm * HH + q * 8;
      v4f acc0 = {0.f,0.f,0.f,0.f}, acc1 = {0.f,0.f,0.f,0.f};
#pragma unroll 4
      for (int k0 = 0; k0 < HH; k0 += 32) {
        v8b a = *(const v8b*)(hp + k0);
        v8b w0 = *(const v8b*)&Wlds[(((k0 >> 3) + q) * 32 + m16) * 8];
        v8b w1 = *(const v8b*)&Wlds[(((k0 >> 3) + q) * 32 + 16 + m16) * 8];
        acc0 = __builtin_amdgcn_mfma_f32_16x16x32_bf16(a, w0, acc0, 0, 0, 0);
        acc1 = __builtin_amdgcn_mfma_f32_16x16x32_bf16(a, w1, acc1, 0, 0, 0);
      }
      acc0 += x0; acc1 += x1;
      u16* hw = h0r + (t & 3) * (BB * HH);
#pragma unroll
      for (int r = 0; r < 4; ++r) {
        float a0 = acc0[r], a1 = acc1[r];
        float p0 = __shfl_xor(a0, 8, 64);
        float p1 = __shfl_xor(a1, 8, 64);
        float iv = lo ? a0 : p0;
        float fv = lo ? p0 : a0;
        float gv = lo ? a1 : p1;
        float ov = lo ? p1 : a1;
        float cn = sigm(fv) * cst[r] + sigm(iv) * tanhf(gv);
        cst[r] = cn;
        float hv = sigm(ov) * tanhf(cn);
        if (lo) stg2_h(&hw[(bq + r) * HH + ubase + j0], f2bf(hv));
      }
      drain_stores();
      __syncthreads();
      bump(&cL0[t]);
    }
  } else if (wg < NA0 + NL0 + NA1) {
    // ================= A1: xp1[t] = W_ih1 @ h0[t] + b1 (rows rbase..rbase+31, K=1024) ========
    const int awg = wg - (NA0 + NL0);
    const int rbase = awg * 32;
    for (int c2 = tid; c2 < 32 * 128; c2 += 256) {
      int r = c2 >> 7, kb = c2 & 127;
      const float* src = Wih1 + (long)(rbase + r) * HH + kb * 8;
      v8b w;
#pragma unroll
      for (int j = 0; j < 8; ++j) w[j] = (short)f2bf(src[j]);
      *(v8b*)&Wlds[(kb * 32 + r) * 8] = w;
    }
    __syncthreads();
    float bias[2];
#pragma unroll
    for (int nt = 0; nt < 2; ++nt) bias[nt] = b1[rbase + nt * 16 + m16];
    for (int t = 0; t < TT; ++t) {
      if (tid == 0) spin_ge(&cL0[t], NL0);
      if (tid == 1 && t >= 4) spin_ge(&cL1[t - 4], NL1);  // xp1 ring back-pressure
      __syncthreads();
      acq_fence();
      const u16* hp = h0r + (t & 3) * (BB * HH) + bm * HH + q * 8;
      v4f acc0 = {0.f,0.f,0.f,0.f}, acc1 = {0.f,0.f,0.f,0.f};
#pragma unroll 4
      for (int k0 = 0; k0 < HH; k0 += 32) {
        v8b a = *(const v8b*)(hp + k0);
        v8b w0 = *(const v8b*)&Wlds[(((k0 >> 3) + q) * 32 + m16) * 8];
        v8b w1 = *(const v8b*)&Wlds[(((k0 >> 3) + q) * 32 + 16 + m16) * 8];
        acc0 = __builtin_amdgcn_mfma_f32_16x16x32_bf16(a, w0, acc0, 0, 0, 0);
        acc1 = __builtin_amdgcn_mfma_f32_16x16x32_bf16(a, w1, acc1, 0, 0, 0);
      }
      const int slot = t & 3;
      v4f v0 = acc0 + bias[0];
      v4f v1 = acc1 + bias[1];
      stg16_f(&xp1[(long)slot * (GG * BB) + (long)(rbase + m16) * BB + bq], v0);
      stg16_f(&xp1[(long)slot * (GG * BB) + (long)(rbase + 16 + m16) * BB + bq], v1);
      drain_stores();
      __syncthreads();
      bump(&cA1[t]);
    }
  } else {
    // ================= L1: gates = xp1 + W_hh1 @ h1[t-1]; cell + last-step capture ============
    const int uwg = wg - (NA0 + NL0 + NA1);
    const int ubase = uwg * 8;
    for (int c2 = tid; c2 < 32 * 128; c2 += 256) {
      int r = c2 >> 7, kb = c2 & 127;
      int grow = (r >> 3) * HH + ubase + (r & 7);
      const float* src = Whh1 + (long)grow * HH + kb * 8;
      v8b w;
#pragma unroll
      for (int j = 0; j < 8; ++j) w[j] = (short)f2bf(src[j]);
      *(v8b*)&Wlds[(kb * 32 + r) * 8] = w;
    }
    __syncthreads();
    const int gi0 = (m16 >> 3);
    const int j0 = m16 & 7;
    const int row0 = gi0 * HH + ubase + j0;
    const int row1 = (2 + gi0) * HH + ubase + j0;
    const bool lo = (m16 < 8);
    float cst[4] = {0.f, 0.f, 0.f, 0.f};
    int len4[4];
#pragma unroll
    for (int r = 0; r < 4; ++r) len4[r] = lens[bq + r];
    for (int t = 0; t < TT; ++t) {
      if (tid == 0) spin_ge(&cA1[t], NA1);
      if (tid == 1 && t >= 1) spin_ge(&cL1[t - 1], NL1);
      __syncthreads();
      acq_fence();
      const float* xpS = xp1 + (long)(t & 3) * (GG * BB);
      v4f x0 = *(const v4f*)&xpS[(long)row0 * BB + bq];
      v4f x1 = *(const v4f*)&xpS[(long)row1 * BB + bq];
      const u16* hp = h1r + ((t + 3) & 3) * (BB * HH) + bm * HH + q * 8;
      v4f acc0 = {0.f,0.f,0.f,0.f}, acc1 = {0.f,0.f,0.f,0.f};
#pragma unroll 4
      for (int k0 = 0; k0 < HH; k0 += 32) {
        v8b a = *(const v8b*)(hp + k0);
        v8b w0 = *(const v8b*)&Wlds[(((k0 >> 3) + q) * 32 + m16) * 8];
        v8b w1 = *(const v8b*)&Wlds[(((k0 >> 3) + q) * 32 + 16 + m16) * 8];
        acc0 = __builtin_amdgcn_mfma_f32_16x16x32_bf16(a, w0, acc0, 0, 0, 0);
        acc1 = __builtin_amdgcn_mfma_f32_16x16x32_bf16(a, w1, acc1, 0, 0, 0);
      }
      acc0 += x0; acc1 += x1;
      u16* hw = h1r + (t & 3) * (BB * HH);
#pragma unroll
      for (int r = 0; r < 4; ++r) {
        float a0 = acc0[r], a1 = acc1[r];
        float p0 = __shfl_xor(a0, 8, 64);
        float p1 = __shfl_xor(a1, 8, 64);
        float iv = lo ? a0 : p0;
        float fv = lo ? p0 : a0;
        float gv = lo ? a1 : p1;
        float ov = lo ? p1 : a1;
        float cn = sigm(fv) * cst[r] + sigm(iv) * tanhf(gv);
        cst[r] = cn;
        float hv = sigm(ov) * tanhf(cn);
        if (lo) {
          stg2_h(&hw[(bq + r) * HH + ubase + j0], f2bf(hv));
          if (t == len4[r] - 1) stg4_f(&lasth[(long)(bq + r) * HH + ubase + j0], hv);
        }
      }
      drain_stores();
      __syncthreads();
      bump(&cL1[t]);
    }
  }
}

// ---------------- final: out = last_h1 @ W_out^T + b_out (all fp32) ----------------
__global__ void out_kernel(const float* __restrict__ lasth, const float* __restrict__ Wout,
                           const float* __restrict__ bout, float* __restrict__ out) {
  int b = blockIdx.x;
  int k = threadIdx.x;
  if (k < 10) {
    float acc = bout[k];
    const float* hb = lasth + (long)b * HH;
    const float* wr = Wout + (long)k * HH;
    for (int j = 0; j < HH; ++j) acc += hb[j] * wr[j];
    out[b * 10 + k] = acc;
  }
}

extern "C" void kernel_launch(void* const* d_in, const int* in_sizes, int n_in,
                              void* d_out, int out_size, void* d_ws, size_t ws_size,
                              hipStream_t stream) {
  const int*   x    = (const int*)d_in[0];
  const float* emb  = (const float*)d_in[1];
  const float* Wih0 = (const float*)d_in[2];
  const float* Whh0 = (const float*)d_in[3];
  const float* b0   = (const float*)d_in[4];
  const float* Wih1 = (const float*)d_in[5];
  const float* Whh1 = (const float*)d_in[6];
  const float* b1   = (const float*)d_in[7];
  const float* Wout = (const float*)d_in[8];
  const float* bout = (const float*)d_in[9];

  char* ws = (char*)d_ws;
  u16*   e16   = (u16*)(ws + 0);            // 33,554,432 B
  float* xp0   = (float*)(ws + 33554432);   // 8 slots * 4096 * 64 * 4 = 8,388,608 B
  float* xp1   = (float*)(ws + 41943040);   // 4 slots * 4096 * 64 * 4 = 4,194,304 B
  u16*   h0r   = (u16*)(ws + 46137344);     // 4 slots * 64 * 1024 * 2 =   524,288 B
  u16*   h1r   = (u16*)(ws + 46661632);     //   524,288 B
  float* lasth = (float*)(ws + 47185920);   //   262,144 B
  int*   lens  = (int*)(ws + 47448064);     //       256 B
  u32*   cnts  = (u32*)(ws + 47448320);     //  4*512*4 = 8,192 B
  u32* cA0 = cnts;
  u32* cL0 = cA0 + 512;
  u32* cA1 = cL0 + 512;
  u32* cL1 = cA1 + 512;
  int cnt_u32s = 4 * 512;

  prep_kernel<<<2048, 256, 0, stream>>>(x, emb, e16, h0r, h1r, lens, cnts, cnt_u32s);
  lstm_persist<<<NWG, 256, 0, stream>>>(e16, Wih0, Whh0, b0, Wih1, Whh1, b1, lens,
                                        xp0, xp1, h0r, h1r, lasth, cA0, cL0, cA1, cL1);
  out_kernel<<<BB, 64, 0, stream>>>(lasth, Wout, bout, (float*)d_out);
}

// Round 6
// 6888.133 us; speedup vs baseline: 1.8498x; 1.8498x over previous
//
#include <hip/hip_runtime.h>
#include <stdint.h>

#define BB 64
#define TT 512
#define EE 512
#define HH 1024
#define GG 4096

#define NSG 64          // WGs per stage
#define XP0_SLOTS 8

typedef short v8b __attribute__((ext_vector_type(8)));
typedef float v4f __attribute__((ext_vector_type(4)));
typedef unsigned short u16;
typedef unsigned int u32;
typedef unsigned long long u64;

__device__ __forceinline__ u16 f2bf(float f) {
  union { float f; u32 i; } v; v.f = f;
  u32 u = v.i;
  return (u16)((u + 0x7FFFu + ((u >> 16) & 1u)) >> 16);
}
__device__ __forceinline__ float sigm(float x) { return 1.0f / (1.0f + __expf(-x)); }

// ---- MALL-coherent accessors, ALL compiler-visible (auto waitcnt), agent scope ----
__device__ __forceinline__ v8b ldb16a(const u16* p) {
  union { v8b b; u64 q[2]; } u;
  u.q[0] = __hip_atomic_load((const u64*)p,     __ATOMIC_RELAXED, __HIP_MEMORY_SCOPE_AGENT);
  u.q[1] = __hip_atomic_load((const u64*)p + 1, __ATOMIC_RELAXED, __HIP_MEMORY_SCOPE_AGENT);
  return u.b;
}
__device__ __forceinline__ v4f ldf16a(const float* p) {
  union { v4f f; u64 q[2]; } u;
  u.q[0] = __hip_atomic_load((const u64*)p,     __ATOMIC_RELAXED, __HIP_MEMORY_SCOPE_AGENT);
  u.q[1] = __hip_atomic_load((const u64*)p + 1, __ATOMIC_RELAXED, __HIP_MEMORY_SCOPE_AGENT);
  return u.f;
}
__device__ __forceinline__ void stg16_f(float* p, v4f v) {
  union { v4f f; u64 q[2]; } u; u.f = v;
  __hip_atomic_store((u64*)p,     u.q[0], __ATOMIC_RELAXED, __HIP_MEMORY_SCOPE_AGENT);
  __hip_atomic_store((u64*)p + 1, u.q[1], __ATOMIC_RELAXED, __HIP_MEMORY_SCOPE_AGENT);
}
__device__ __forceinline__ void stg2_h(u16* p, u16 v) {
  __hip_atomic_store(p, v, __ATOMIC_RELAXED, __HIP_MEMORY_SCOPE_AGENT);
}
__device__ __forceinline__ void stg4_f(float* p, float v) {
  __hip_atomic_store(p, v, __ATOMIC_RELAXED, __HIP_MEMORY_SCOPE_AGENT);
}
__device__ __forceinline__ void drain_stores() {
  asm volatile("s_waitcnt vmcnt(0)" ::: "memory");
}
__device__ __forceinline__ void compiler_barrier() {
  asm volatile("" ::: "memory");
}

// ---------------- prep: gather embeddings (fp32->bf16), zero flags + h rings, lens ----------
__global__ void prep_kernel(const int* __restrict__ x, const float* __restrict__ emb,
                            u16* __restrict__ e16, u16* __restrict__ h0r, u16* __restrict__ h1r,
                            int* __restrict__ lens, u32* flags, int flag_u32s) {
  long stride = (long)gridDim.x * blockDim.x;
  long gid = (long)blockIdx.x * blockDim.x + threadIdx.x;
  const long totalE = (long)BB * TT * EE;
  for (long i = gid; i < totalE; i += stride) {
    int d = (int)(i % EE);
    long bt = i / EE;
    int tok = x[bt];
    e16[i] = f2bf(emb[(long)tok * EE + d]);
  }
  for (long i = gid; i < (long)flag_u32s; i += stride) flags[i] = 0u;
  const long ringN = 4L * BB * HH;
  for (long i = gid; i < ringN; i += stride) { h0r[i] = 0; h1r[i] = 0; }
  int gwave = (int)(gid >> 6);
  int lane = (int)(gid & 63);
  if (gwave < BB) {
    int cnt = 0;
    for (int t2 = lane; t2 < TT; t2 += 64) cnt += (x[gwave * TT + t2] == 0) ? 1 : 0;
    for (int off = 32; off; off >>= 1) cnt += __shfl_down(cnt, off, 64);
    if (lane == 0) lens[gwave] = TT - cnt;
  }
}

// ---------------- flag helpers: monotone per-WG counters in MALL ----------------
__device__ __forceinline__ void spinf(const u32* f, u32 v) {
  while (__hip_atomic_load(f, __ATOMIC_RELAXED, __HIP_MEMORY_SCOPE_AGENT) < v)
    __builtin_amdgcn_s_sleep(1);
}
__device__ __forceinline__ void post(u32* f, u32 v) {
  if (threadIdx.x == 0)
    __hip_atomic_store(f, v, __ATOMIC_RELAXED, __HIP_MEMORY_SCOPE_AGENT);
}

extern __shared__ short Wlds[];  // dynamic, 128 KB

// one 32-wide K-block: 4 ds_read_b128 (4 n-tiles of 16 rows) + 4 MFMA
#define KQUAD(FR, PK) \
  { const short* wb = &Wlds[(((PK) * 4 + q) * 64 + m16) * 8]; \
    v8b w0 = *(const v8b*)(wb); \
    v8b w1 = *(const v8b*)(wb + 128); \
    v8b w2 = *(const v8b*)(wb + 256); \
    v8b w3 = *(const v8b*)(wb + 384); \
    a0 = __builtin_amdgcn_mfma_f32_16x16x32_bf16(FR, w0, a0, 0, 0, 0); \
    a1 = __builtin_amdgcn_mfma_f32_16x16x32_bf16(FR, w1, a1, 0, 0, 0); \
    a2 = __builtin_amdgcn_mfma_f32_16x16x32_bf16(FR, w2, a2, 0, 0, 0); \
    a3 = __builtin_amdgcn_mfma_f32_16x16x32_bf16(FR, w3, a3, 0, 0, 0); }

// K=1024 MALL-coherent h read + MFMA, double-banked 8+8 (compiler-managed waitcnts)
__device__ __forceinline__ void khloop(const u16* hp, int q, int m16,
                                       v4f& a0, v4f& a1, v4f& a2, v4f& a3) {
  v8b A[8], B[8];
#pragma unroll
  for (int i = 0; i < 8; ++i) A[i] = ldb16a(hp + i * 32);
#pragma unroll
  for (int i = 0; i < 8; ++i) B[i] = ldb16a(hp + (8 + i) * 32);
#pragma unroll
  for (int i = 0; i < 8; ++i) KQUAD(A[i], i);
#pragma unroll
  for (int i = 0; i < 8; ++i) A[i] = ldb16a(hp + (16 + i) * 32);
#pragma unroll
  for (int i = 0; i < 8; ++i) KQUAD(B[i], 8 + i);
#pragma unroll
  for (int i = 0; i < 8; ++i) B[i] = ldb16a(hp + (24 + i) * 32);
#pragma unroll
  for (int i = 0; i < 8; ++i) KQUAD(A[i], 16 + i);
#pragma unroll
  for (int i = 0; i < 8; ++i) KQUAD(B[i], 24 + i);
}

// ---------------- persistent pipeline kernel: 4 stages x 64 WGs, 1 WG/CU ----------------
__global__ __launch_bounds__(256, 1) void lstm_persist(
    const u16* __restrict__ e16,
    const float* __restrict__ Wih0, const float* __restrict__ Whh0, const float* __restrict__ b0,
    const float* __restrict__ Wih1, const float* __restrict__ Whh1, const float* __restrict__ b1,
    const int* __restrict__ lens,
    float* __restrict__ xp0, float* __restrict__ xp1,
    u16* __restrict__ h0r, u16* __restrict__ h1r,
    float* __restrict__ lasth,
    u32* fA0, u32* fL0, u32* fA1, u32* fL1) {
  const int wg = blockIdx.x;
  const int tid = threadIdx.x;
  const int wave = tid >> 6;
  const int lane = tid & 63;
  const int m16 = lane & 15;
  const int q = lane >> 4;
  const int bm = wave * 16 + m16;    // A-frag batch row (M)
  const int bq = wave * 16 + q * 4;  // C-tile batch base (row = q*4+reg)
  const int stage = wg >> 6;
  const int sid = wg & 63;

  if (stage == 0) {
    // ===== A0: xp0[t] = W_ih0 @ e_t + b0 (rows sid*64..+63, K=512) =====
    const int rbase = sid * 64;
    for (int c2 = tid; c2 < 64 * 64; c2 += 256) {
      int r = c2 >> 6, kb = c2 & 63;
      const float* src = Wih0 + (long)(rbase + r) * EE + kb * 8;
      v8b w;
#pragma unroll
      for (int j = 0; j < 8; ++j) w[j] = (short)f2bf(src[j]);
      *(v8b*)&Wlds[(kb * 64 + r) * 8] = w;
    }
    __syncthreads();
    float bias[4];
#pragma unroll
    for (int nt = 0; nt < 4; ++nt) bias[nt] = b0[rbase + nt * 16 + m16];
    for (int t = 0; t < TT; ++t) {
      if (tid < NSG && t >= XP0_SLOTS) spinf(&fL0[tid], (u32)(t - XP0_SLOTS + 1));
      __syncthreads();
      compiler_barrier();
      v4f a0 = {0,0,0,0}, a1 = {0,0,0,0}, a2 = {0,0,0,0}, a3 = {0,0,0,0};
      const u16* ap = e16 + (long)bm * (TT * EE) + (long)t * EE + q * 8;
#pragma unroll
      for (int kb = 0; kb < 16; ++kb) {
        v8b fr = *(const v8b*)(ap + kb * 32);  // plain cached load (e16 static)
        KQUAD(fr, kb);
      }
      float* xpS = xp0 + (long)(t & (XP0_SLOTS - 1)) * (GG * BB);
      stg16_f(&xpS[(long)(rbase + 0 * 16 + m16) * BB + bq], a0 + bias[0]);
      stg16_f(&xpS[(long)(rbase + 1 * 16 + m16) * BB + bq], a1 + bias[1]);
      stg16_f(&xpS[(long)(rbase + 2 * 16 + m16) * BB + bq], a2 + bias[2]);
      stg16_f(&xpS[(long)(rbase + 3 * 16 + m16) * BB + bq], a3 + bias[3]);
      drain_stores();
      __syncthreads();
      post(&fA0[sid], (u32)(t + 1));
    }
  } else if (stage == 1) {
    // ===== L0: gates = xp0 + W_hh0 @ h0[t-1]; 16 units, lane-local cell =====
    const int ubase = sid * 16;
    for (int c2 = tid; c2 < 64 * 128; c2 += 256) {
      int r = c2 >> 7, kb = c2 & 127;
      int grow = (r >> 4) * HH + ubase + (r & 15);  // rows: [i 0..15 | f | g | o]
      const float* src = Whh0 + (long)grow * HH + kb * 8;
      v8b w;
#pragma unroll
      for (int j = 0; j < 8; ++j) w[j] = (short)f2bf(src[j]);
      *(v8b*)&Wlds[(kb * 64 + r) * 8] = w;
    }
    __syncthreads();
    float cst[4] = {0.f, 0.f, 0.f, 0.f};
    for (int t = 0; t < TT; ++t) {
      if (tid < 64) spinf(&fA0[tid], (u32)(t + 1));
      else if (tid < 128) { if (t >= 1) spinf(&fL0[tid - 64], (u32)t); }
      else if (tid < 192) { if (t >= 4) spinf(&fA1[tid - 128], (u32)(t - 3)); }
      __syncthreads();
      compiler_barrier();
      const float* xpS = xp0 + (long)(t & (XP0_SLOTS - 1)) * (GG * BB);
      v4f xq0 = ldf16a(&xpS[(long)(0 * HH + ubase + m16) * BB + bq]);
      v4f xq1 = ldf16a(&xpS[(long)(1 * HH + ubase + m16) * BB + bq]);
      v4f xq2 = ldf16a(&xpS[(long)(2 * HH + ubase + m16) * BB + bq]);
      v4f xq3 = ldf16a(&xpS[(long)(3 * HH + ubase + m16) * BB + bq]);
      v4f a0 = {0,0,0,0}, a1 = {0,0,0,0}, a2 = {0,0,0,0}, a3 = {0,0,0,0};
      const u16* hp = h0r + ((t + 3) & 3) * (BB * HH) + bm * HH + q * 8;
      khloop(hp, q, m16, a0, a1, a2, a3);
      a0 += xq0; a1 += xq1; a2 += xq2; a3 += xq3;   // i, f, g, o
      u16* hw = h0r + (t & 3) * (BB * HH);
#pragma unroll
      for (int r = 0; r < 4; ++r) {
        float cn = sigm(a1[r]) * cst[r] + sigm(a0[r]) * tanhf(a2[r]);
        cst[r] = cn;
        float hv = sigm(a3[r]) * tanhf(cn);
        stg2_h(&hw[(bq + r) * HH + ubase + m16], f2bf(hv));
      }
      drain_stores();
      __syncthreads();
      post(&fL0[sid], (u32)(t + 1));
    }
  } else if (stage == 2) {
    // ===== A1: xp1[t] = W_ih1 @ h0[t] + b1 (rows sid*64..+63, K=1024) =====
    const int rbase = sid * 64;
    for (int c2 = tid; c2 < 64 * 128; c2 += 256) {
      int r = c2 >> 7, kb = c2 & 127;
      const float* src = Wih1 + (long)(rbase + r) * HH + kb * 8;
      v8b w;
#pragma unroll
      for (int j = 0; j < 8; ++j) w[j] = (short)f2bf(src[j]);
      *(v8b*)&Wlds[(kb * 64 + r) * 8] = w;
    }
    __syncthreads();
    float bias[4];
#pragma unroll
    for (int nt = 0; nt < 4; ++nt) bias[nt] = b1[rbase + nt * 16 + m16];
    for (int t = 0; t < TT; ++t) {
      if (tid < 64) spinf(&fL0[tid], (u32)(t + 1));
      else if (tid < 128) { if (t >= 4) spinf(&fL1[tid - 64], (u32)(t - 3)); }
      __syncthreads();
      compiler_barrier();
      v4f a0 = {0,0,0,0}, a1 = {0,0,0,0}, a2 = {0,0,0,0}, a3 = {0,0,0,0};
      const u16* hp = h0r + (t & 3) * (BB * HH) + bm * HH + q * 8;
      khloop(hp, q, m16, a0, a1, a2, a3);
      float* xpS = xp1 + (long)(t & 3) * (GG * BB);
      stg16_f(&xpS[(long)(rbase + 0 * 16 + m16) * BB + bq], a0 + bias[0]);
      stg16_f(&xpS[(long)(rbase + 1 * 16 + m16) * BB + bq], a1 + bias[1]);
      stg16_f(&xpS[(long)(rbase + 2 * 16 + m16) * BB + bq], a2 + bias[2]);
      stg16_f(&xpS[(long)(rbase + 3 * 16 + m16) * BB + bq], a3 + bias[3]);
      drain_stores();
      __syncthreads();
      post(&fA1[sid], (u32)(t + 1));
    }
  } else {
    // ===== L1: gates = xp1 + W_hh1 @ h1[t-1]; cell + last-step capture =====
    const int ubase = sid * 16;
    for (int c2 = tid; c2 < 64 * 128; c2 += 256) {
      int r = c2 >> 7, kb = c2 & 127;
      int grow = (r >> 4) * HH + ubase + (r & 15);
      const float* src = Whh1 + (long)grow * HH + kb * 8;
      v8b w;
#pragma unroll
      for (int j = 0; j < 8; ++j) w[j] = (short)f2bf(src[j]);
      *(v8b*)&Wlds[(kb * 64 + r) * 8] = w;
    }
    __syncthreads();
    float cst[4] = {0.f, 0.f, 0.f, 0.f};
    int cap[4];
#pragma unroll
    for (int r = 0; r < 4; ++r) {
      int l = lens[bq + r];
      cap[r] = (l > 0) ? (l - 1) : (TT - 1);
    }
    for (int t = 0; t < TT; ++t) {
      if (tid < 64) spinf(&fA1[tid], (u32)(t + 1));
      else if (tid < 128) { if (t >= 1) spinf(&fL1[tid - 64], (u32)t); }
      __syncthreads();
      compiler_barrier();
      const float* xpS = xp1 + (long)(t & 3) * (GG * BB);
      v4f xq0 = ldf16a(&xpS[(long)(0 * HH + ubase + m16) * BB + bq]);
      v4f xq1 = ldf16a(&xpS[(long)(1 * HH + ubase + m16) * BB + bq]);
      v4f xq2 = ldf16a(&xpS[(long)(2 * HH + ubase + m16) * BB + bq]);
      v4f xq3 = ldf16a(&xpS[(long)(3 * HH + ubase + m16) * BB + bq]);
      v4f a0 = {0,0,0,0}, a1 = {0,0,0,0}, a2 = {0,0,0,0}, a3 = {0,0,0,0};
      const u16* hp = h1r + ((t + 3) & 3) * (BB * HH) + bm * HH + q * 8;
      khloop(hp, q, m16, a0, a1, a2, a3);
      a0 += xq0; a1 += xq1; a2 += xq2; a3 += xq3;
      u16* hw = h1r + (t & 3) * (BB * HH);
#pragma unroll
      for (int r = 0; r < 4; ++r) {
        float cn = sigm(a1[r]) * cst[r] + sigm(a0[r]) * tanhf(a2[r]);
        cst[r] = cn;
        float hv = sigm(a3[r]) * tanhf(cn);
        stg2_h(&hw[(bq + r) * HH + ubase + m16], f2bf(hv));
        if (t == cap[r]) stg4_f(&lasth[(long)(bq + r) * HH + ubase + m16], hv);
      }
      drain_stores();
      __syncthreads();
      post(&fL1[sid], (u32)(t + 1));
    }
  }
}

// ---------------- final: out = last_h1 @ W_out^T + b_out (all fp32) ----------------
__global__ void out_kernel(const float* __restrict__ lasth, const float* __restrict__ Wout,
                           const float* __restrict__ bout, float* __restrict__ out) {
  int b = blockIdx.x;
  int k = threadIdx.x;
  if (k < 10) {
    float acc = bout[k];
    const float* hb = lasth + (long)b * HH;
    const float* wr = Wout + (long)k * HH;
    for (int j = 0; j < HH; ++j) acc += hb[j] * wr[j];
    out[b * 10 + k] = acc;
  }
}

extern "C" void kernel_launch(void* const* d_in, const int* in_sizes, int n_in,
                              void* d_out, int out_size, void* d_ws, size_t ws_size,
                              hipStream_t stream) {
  const int*   x    = (const int*)d_in[0];
  const float* emb  = (const float*)d_in[1];
  const float* Wih0 = (const float*)d_in[2];
  const float* Whh0 = (const float*)d_in[3];
  const float* b0   = (const float*)d_in[4];
  const float* Wih1 = (const float*)d_in[5];
  const float* Whh1 = (const float*)d_in[6];
  const float* b1   = (const float*)d_in[7];
  const float* Wout = (const float*)d_in[8];
  const float* bout = (const float*)d_in[9];

  char* ws = (char*)d_ws;
  u16*   e16   = (u16*)(ws + 0);            // 33,554,432 B
  float* xp0   = (float*)(ws + 33554432);   // 8 slots * 4096*64*4 = 8,388,608 B
  float* xp1   = (float*)(ws + 41943040);   // 4 slots = 4,194,304 B
  u16*   h0r   = (u16*)(ws + 46137344);     // 524,288 B
  u16*   h1r   = (u16*)(ws + 46661632);     // 524,288 B
  float* lasth = (float*)(ws + 47185920);   // 262,144 B
  int*   lens  = (int*)(ws + 47448064);     // 256 B
  u32*   flags = (u32*)(ws + 47448320);     // 1,024 B
  u32* fA0 = flags;
  u32* fL0 = fA0 + NSG;
  u32* fA1 = fL0 + NSG;
  u32* fL1 = fA1 + NSG;
  int flag_u32s = 4 * NSG;

  hipFuncSetAttribute((const void*)lstm_persist,
                      hipFuncAttributeMaxDynamicSharedMemorySize, 131072);

  prep_kernel<<<2048, 256, 0, stream>>>(x, emb, e16, h0r, h1r, lens, flags, flag_u32s);
  lstm_persist<<<4 * NSG, 256, 131072, stream>>>(e16, Wih0, Whh0, b0, Wih1, Whh1, b1, lens,
                                                 xp0, xp1, h0r, h1r, lasth, fA0, fL0, fA1, fL1);
  out_kernel<<<BB, 64, 0, stream>>>(lasth, Wout, bout, (float*)d_out);
}